// Round 1
// baseline (224.750 us; speedup 1.0000x reference)
//
#include <hip/hip_runtime.h>

// WindowSlice: B=64, T=4096, C=128 fp32. L = ceil(0.9*T) = 3687.
// out[b,i,c] = lerp(x[b, starts[b]+lo(i), c], x[b, starts[b]+lo(i)+1, c], w(i))
// where t = clip(i * L/(T-1), 0, L-1), lo = min(floor(t), L-2), w = t - lo.

constexpr int B_ = 64;
constexpr int T_ = 4096;
constexpr int C_ = 128;
constexpr int L_ = 3687;          // ceil(0.9 * 4096)
constexpr int C4 = C_ / 4;        // 32 float4 per row

__global__ __launch_bounds__(256)
void WindowSlice_kernel(const float4* __restrict__ x,
                        const int*    __restrict__ starts,
                        float4*       __restrict__ out) {
    const int tid = blockIdx.x * 256 + threadIdx.x;   // one float4 per thread
    const int row = tid >> 5;                         // / C4 (32)
    const int c4  = tid & 31;
    const int b   = row >> 12;                        // / T (4096)
    const int i   = row & (T_ - 1);

    // np.interp query point in double for robust lo/w (few F64 ops, negligible)
    const double step = (double)L_ / (double)(T_ - 1);
    double t = (double)i * step;
    if (t > (double)(L_ - 1)) t = (double)(L_ - 1);
    int lo = (int)t;
    if (lo > L_ - 2) lo = L_ - 2;
    const float w = (float)(t - (double)lo);

    const int start = starts[b];
    const long long base = ((long long)b * T_ + start + lo) * C4 + c4;

    const float4 vlo = x[base];
    const float4 vhi = x[base + C4];

    float4 o;
    o.x = fmaf(w, vhi.x - vlo.x, vlo.x);
    o.y = fmaf(w, vhi.y - vlo.y, vlo.y);
    o.z = fmaf(w, vhi.z - vlo.z, vlo.z);
    o.w = fmaf(w, vhi.w - vlo.w, vlo.w);

    out[(long long)row * C4 + c4] = o;
}

extern "C" void kernel_launch(void* const* d_in, const int* in_sizes, int n_in,
                              void* d_out, int out_size, void* d_ws, size_t ws_size,
                              hipStream_t stream) {
    const float4* x      = (const float4*)d_in[0];
    const int*    starts = (const int*)d_in[1];
    float4*       out    = (float4*)d_out;

    const int total_f4 = B_ * T_ * C4;               // 8,388,608
    const int blocks   = total_f4 / 256;             // 32,768
    WindowSlice_kernel<<<blocks, 256, 0, stream>>>(x, starts, out);
}